// Round 8
// baseline (197.894 us; speedup 1.0000x reference)
//
#include <hip/hip_runtime.h>

#define NB 4
#define NC 64
#define NH 256
#define NW 256
#define TH 32                  // output rows per block (4 waves x 8 rows)
#define SROWS (TH + 6)         // 38 staged input rows (incl. +/-3 halo)
#define LROW 256               // LDS row: no side pads — DPP zero-fill IS the pad

// ---------- phase 1: per-pixel g only (inv2 re-derived in phase 2, bitwise same) ----------
__global__ __launch_bounds__(256)
void wprep(const float* __restrict__ persp,
           const float* __restrict__ alpha_p,
           const float* __restrict__ beta_p,
           const float* __restrict__ gamma_p,
           float* __restrict__ wg)
{
    const float alpha = alpha_p[0];
    const float beta  = beta_p[0];
    const float gamma = gamma_p[0];
    const int i = (blockIdx.x * 256 + threadIdx.x) * 4;
    const float4 p = *(const float4*)(persp + i);
    const float pa[4] = {p.x, p.y, p.z, p.w};
    float g[4];
    #pragma unroll
    for (int k = 0; k < 4; ++k) {
        const float z  = fmaf(beta, pa[k], gamma);
        const float sg = __builtin_amdgcn_rcpf(1.0f + __expf(-z));
        const float sigma = fmaxf(alpha * sg, 1e-4f);
        const float t  = 0.5f * __builtin_amdgcn_rcpf(sigma * sigma);
        g[k] = __expf(-t);
    }
    *(float4*)(wg + i) = make_float4(g[0], g[1], g[2], g[3]);
}

// lane i <- lane i-1 (data shifts toward higher lanes); lane 0 gets 0.0f.
// Wave spans the full 256-px image row, so the zero-fill IS the left pad.
__device__ __forceinline__ float dpp_shr1(float v) {
    return __int_as_float(__builtin_amdgcn_update_dpp(
        0, __float_as_int(v), 0x138 /*WAVE_SHR1*/, 0xf, 0xf, true));
}
// lane i <- lane i+1; lane 63 gets 0.0f (right pad).
__device__ __forceinline__ float dpp_shl1(float v) {
    return __int_as_float(__builtin_amdgcn_update_dpp(
        0, __float_as_int(v), 0x130 /*WAVE_SHL1*/, 0xf, 0xf, true));
}

// ---------- phase 2: DPP-halo window at 4 waves/SIMD ----------
// Model recalibration (r7): VALU work = ~56 us*SIMD total; time == work /
// (4 SIMD * VALUBusy). All prior rounds pinned at 3 waves/SIMD (reg budget
// 168 at (256,3)) -> VALUBusy ~30%. Lever = wave cap, not latency sources.
// Live set here ~80 (win 28 + rolling ws 8 + transients) -> (256,4)=128 fits.
// Ledger: (256,4)+live~110 SPILLED (r4, 150us). Spill tell: WRITE_SIZE>150MB.
__global__ __launch_bounds__(256, 4)
void adaptive_gauss7(const float* __restrict__ x,
                     const float* __restrict__ wgp,
                     float* __restrict__ out)
{
    __shared__ float lds[SROWS * LROW];   // 38,912 B -> 4 blocks/CU by LDS

    const int tid  = threadIdx.x;
    const int lane = tid & 63;
    const int wv   = tid >> 6;            // 4 waves x 8 rows = 32 rows
    const int c    = blockIdx.x;
    const int h0   = blockIdx.y * TH;
    const int b    = blockIdx.z;
    const int colbase = lane * 4;         // output cols colbase..colbase+3
    const int rg      = h0 + wv * 8;      // first output row of this wave

    const float* xc   = x   + (size_t)(b * NC + c) * NH * NW;
    float*       outp = out + (size_t)(b * NC + c) * NH * NW;
    const float* wrow = wgp + (size_t)b * NH * NW;

    // first row's g — issued before staging, completes under the DMA drain
    float4 wcur = *(const float4*)(wrow + (size_t)rg * NW + colbase);

    // async stage: wave-interleaved rows, DMA straight to LDS (no pads)
    for (int r = wv; r < SROWS; r += 4) {
        const int gr = h0 - 3 + r;                     // wave-uniform bound
        if ((unsigned)gr < NH) {
            __builtin_amdgcn_global_load_lds(
                (const __attribute__((address_space(1))) void*)(xc + (size_t)gr * NW + colbase),
                (__attribute__((address_space(3))) void*)&lds[r * LROW],
                16, 0, 0);
        } else {
            *(float4*)&lds[r * LROW + colbase] = make_float4(0.f, 0.f, 0.f, 0.f);
        }
    }
    __syncthreads();

    // window: 7 rows x 4 cols (own columns only). Row (wv*8+o+j) in slot (o+j)%7.
    float win[7][4];
    #pragma unroll
    for (int r = 0; r < 7; ++r) {
        const float4 a = *(const float4*)&lds[(wv * 8 + r) * LROW + colbase];
        win[r][0] = a.x; win[r][1] = a.y; win[r][2] = a.z; win[r][3] = a.w;
    }

    #pragma unroll
    for (int o = 0; o < 8; ++o) {
        // rolling 1-ahead g prefetch (r6 proved hoist-vs-rolling time-neutral;
        // rolling costs 8 live regs instead of 32 — that's the point here)
        float4 wnxt;
        if (o < 7)
            wnxt = *(const float4*)(wrow + (size_t)(rg + o + 1) * NW + colbase);

        // per-pixel weight powers (inv2 derived with wprep's exact op sequence)
        const float gk[4] = {wcur.x, wcur.y, wcur.z, wcur.w};
        float g[4], p4[4], p9[4], inv2[4];
        #pragma unroll
        for (int k = 0; k < 4; ++k) {
            g[k] = gk[k];
            const float g2 = g[k] * g[k];
            p4[k] = g2 * g2;
            p9[k] = p4[k] * p4[k] * g[k];
            const float S  = fmaf(2.0f, (g[k] + p4[k]) + p9[k], 1.0f);
            const float iv = __builtin_amdgcn_rcpf(S);
            inv2[k] = iv * iv;
        }

        // horizontal pass per row: 1 stored b128 + 6 DPP halos -> 10-wide window
        float s0[4], s1[4], s2[4], s3[4];   // pair-sum slots per pixel
        #pragma unroll
        for (int j = 0; j < 7; ++j) {
            const int s = (o + j) % 7;      // static after unroll
            const float w[10] = {
                dpp_shr1(win[s][1]),        // col -3
                dpp_shr1(win[s][2]),        // col -2
                dpp_shr1(win[s][3]),        // col -1
                win[s][0], win[s][1], win[s][2], win[s][3],
                dpp_shl1(win[s][0]),        // col +4
                dpp_shl1(win[s][1]),        // col +5
                dpp_shl1(win[s][2])         // col +6
            };
            #pragma unroll
            for (int k = 0; k < 4; ++k) {
                const float rs = fmaf(p9[k], w[k]     + w[k + 6],
                                 fmaf(p4[k], w[k + 1] + w[k + 5],
                                 fmaf(g[k],  w[k + 2] + w[k + 4],
                                             w[k + 3])));
                if      (j == 0) s0[k] = rs;
                else if (j == 1) s1[k] = rs;
                else if (j == 2) s2[k] = rs;
                else if (j == 3) s3[k] = rs;
                else if (j == 4) s2[k] = s2[k] + rs;
                else if (j == 5) s1[k] = s1[k] + rs;
                else             s0[k] = s0[k] + rs;
            }
        }

        // vertical combine — same association as rounds 0-7
        float res[4];
        #pragma unroll
        for (int k = 0; k < 4; ++k) {
            res[k] = fmaf(p9[k], s0[k],
                     fmaf(p4[k], s1[k],
                     fmaf(g[k],  s2[k], s3[k]))) * inv2[k];
        }
        *(float4*)(outp + (size_t)(rg + o) * NW + colbase) =
            make_float4(res[0], res[1], res[2], res[3]);

        // refill the dead slot: ONE b128 (own 4 columns only)
        if (o < 7) {
            const float4 a = *(const float4*)&lds[(wv * 8 + o + 7) * LROW + colbase];
            win[o % 7][0] = a.x; win[o % 7][1] = a.y;
            win[o % 7][2] = a.z; win[o % 7][3] = a.w;
            wcur = wnxt;
        }
    }
}

extern "C" void kernel_launch(void* const* d_in, const int* in_sizes, int n_in,
                              void* d_out, int out_size, void* d_ws, size_t ws_size,
                              hipStream_t stream) {
    const float* x     = (const float*)d_in[0];
    const float* persp = (const float*)d_in[1];
    const float* alpha = (const float*)d_in[2];
    const float* beta  = (const float*)d_in[3];
    const float* gamma = (const float*)d_in[4];
    float* outp        = (float*)d_out;
    float* wg          = (float*)d_ws;       // 4*256*256 floats = 1 MiB

    wprep<<<dim3((NB * NH * NW) / 1024), dim3(256), 0, stream>>>(persp, alpha, beta, gamma, wg);
    adaptive_gauss7<<<dim3(NC, NH / TH, NB), dim3(256), 0, stream>>>(x, wg, outp);
}

// Round 9
// 138.034 us; speedup vs baseline: 1.4337x; 1.4337x over previous
//
#include <hip/hip_runtime.h>

#define NB 4
#define NC 64
#define NH 256
#define NW 256
#define CPB 4                  // channels per block, pipelined through 2 LDS buffers
#define TH 32                  // output rows per block (4 waves x 8 rows)
#define SROWS (TH + 6)         // 38 staged input rows (incl. +/-3 halo)
#define LROW 256               // LDS row: no side pads — DPP zero-fill IS the pad

// ---------- phase 1: per-pixel g only (inv2 re-derived in phase 2, bitwise same) ----------
__global__ __launch_bounds__(256)
void wprep(const float* __restrict__ persp,
           const float* __restrict__ alpha_p,
           const float* __restrict__ beta_p,
           const float* __restrict__ gamma_p,
           float* __restrict__ wg)
{
    const float alpha = alpha_p[0];
    const float beta  = beta_p[0];
    const float gamma = gamma_p[0];
    const int i = (blockIdx.x * 256 + threadIdx.x) * 4;
    const float4 p = *(const float4*)(persp + i);
    const float pa[4] = {p.x, p.y, p.z, p.w};
    float g[4];
    #pragma unroll
    for (int k = 0; k < 4; ++k) {
        const float z  = fmaf(beta, pa[k], gamma);
        const float sg = __builtin_amdgcn_rcpf(1.0f + __expf(-z));
        const float sigma = fmaxf(alpha * sg, 1e-4f);
        const float t  = 0.5f * __builtin_amdgcn_rcpf(sigma * sigma);
        g[k] = __expf(-t);
    }
    *(float4*)(wg + i) = make_float4(g[0], g[1], g[2], g[3]);
}

// lane i <- lane i-1; lane 0 gets 0.0f (wave spans the image row -> zero-fill IS the pad)
__device__ __forceinline__ float dpp_shr1(float v) {
    return __int_as_float(__builtin_amdgcn_update_dpp(
        0, __float_as_int(v), 0x138 /*WAVE_SHR1*/, 0xf, 0xf, true));
}
// lane i <- lane i+1; lane 63 gets 0.0f (right pad)
__device__ __forceinline__ float dpp_shl1(float v) {
    return __int_as_float(__builtin_amdgcn_update_dpp(
        0, __float_as_int(v), 0x130 /*WAVE_SHL1*/, 0xf, 0xf, true));
}

// ---------- phase 2: channel-pipelined double-buffer + DPP-halo window ----------
// Model (r8 closed it): the invariant ~43us @ VALUBusy 30% was the monolithic
// stage->barrier->compute shape: waves idle through every stage phase, and
// lockstep-dispatched blocks stage simultaneously (HBM burst) instead of
// covering each other. r8 also proved (256,4) ALWAYS spills (3rd time) and
// that more waves alone don't raise issue rate.
// This round: each block runs CPB=4 channels; while computing channel ci from
// buffer A, the DMA for ci+1 fills buffer B. The __syncthreads at loop top
// drains a DMA that had a full compute phase (~4300cyc) to complete -> free.
// Waves barrier-idle only for the first stage.
__global__ __launch_bounds__(256, 3)
void adaptive_gauss7(const float* __restrict__ x,
                     const float* __restrict__ wgp,
                     float* __restrict__ out)
{
    __shared__ float lds[2][SROWS * LROW];   // 2 x 38,912 B = 77,824 B -> 2 blocks/CU

    const int tid  = threadIdx.x;
    const int lane = tid & 63;
    const int wv   = tid >> 6;            // 4 waves x 8 rows = 32 rows
    const int cg   = blockIdx.x;          // 16 channel groups of CPB=4
    const int h0   = blockIdx.y * TH;
    const int b    = blockIdx.z;
    const int colbase = lane * 4;         // output cols colbase..colbase+3
    const int rg      = h0 + wv * 8;      // first output row of this wave
    const int c0      = cg * CPB;

    const float* xb   = x   + (size_t)b * NC * NH * NW;
    float*       outb = out + (size_t)b * NC * NH * NW;
    const float* wrow = wgp + (size_t)b * NH * NW;

    // stage channel c's 38-row tile into lds[buf] (async DMA, wave-interleaved)
    auto stage = [&](int buf, int c) {
        const float* xc = xb + (size_t)c * NH * NW;
        for (int r = wv; r < SROWS; r += 4) {
            const int gr = h0 - 3 + r;                 // wave-uniform bound
            if ((unsigned)gr < NH) {
                __builtin_amdgcn_global_load_lds(
                    (const __attribute__((address_space(1))) void*)(xc + (size_t)gr * NW + colbase),
                    (__attribute__((address_space(3))) void*)&lds[buf][r * LROW],
                    16, 0, 0);
            } else {
                *(float4*)&lds[buf][r * LROW + colbase] = make_float4(0.f, 0.f, 0.f, 0.f);
            }
        }
    };

    stage(0, c0);                         // prologue: only serialized stage

    // wg for this wave's 8 rows — SAME for all CPB channels, hoisted once.
    // Issued while the first DMA drains.
    float4 wsg[8];
    #pragma unroll
    for (int o = 0; o < 8; ++o)
        wsg[o] = *(const float4*)(wrow + (size_t)(rg + o) * NW + colbase);

    for (int ci = 0; ci < CPB; ++ci) {
        __syncthreads();                  // buffer ci&1 ready (drain ~free in steady state)
        if (ci + 1 < CPB)
            stage((ci + 1) & 1, c0 + ci + 1);   // overlap next DMA with this compute

        const float* ldsc = lds[ci & 1];
        float*       outp = outb + (size_t)(c0 + ci) * NH * NW;

        // window: 7 rows x 4 own cols. Tile row (wv*8+o+j) lives in slot (o+j)%7.
        float win[7][4];
        #pragma unroll
        for (int r = 0; r < 7; ++r) {
            const float4 a = *(const float4*)&ldsc[(wv * 8 + r) * LROW + colbase];
            win[r][0] = a.x; win[r][1] = a.y; win[r][2] = a.z; win[r][3] = a.w;
        }

        #pragma unroll
        for (int o = 0; o < 8; ++o) {
            // per-pixel weight powers (inv2 via wprep's exact op sequence)
            const float gk[4] = {wsg[o].x, wsg[o].y, wsg[o].z, wsg[o].w};
            float g[4], p4[4], p9[4], inv2[4];
            #pragma unroll
            for (int k = 0; k < 4; ++k) {
                g[k] = gk[k];
                const float g2 = g[k] * g[k];
                p4[k] = g2 * g2;
                p9[k] = p4[k] * p4[k] * g[k];
                const float S  = fmaf(2.0f, (g[k] + p4[k]) + p9[k], 1.0f);
                const float iv = __builtin_amdgcn_rcpf(S);
                inv2[k] = iv * iv;
            }

            // horizontal: 1 stored b128 + 6 DPP halos -> 10-wide window
            float s0[4], s1[4], s2[4], s3[4];
            #pragma unroll
            for (int j = 0; j < 7; ++j) {
                const int s = (o + j) % 7;      // static after unroll
                const float w[10] = {
                    dpp_shr1(win[s][1]),        // col -3
                    dpp_shr1(win[s][2]),        // col -2
                    dpp_shr1(win[s][3]),        // col -1
                    win[s][0], win[s][1], win[s][2], win[s][3],
                    dpp_shl1(win[s][0]),        // col +4
                    dpp_shl1(win[s][1]),        // col +5
                    dpp_shl1(win[s][2])         // col +6
                };
                #pragma unroll
                for (int k = 0; k < 4; ++k) {
                    const float rs = fmaf(p9[k], w[k]     + w[k + 6],
                                     fmaf(p4[k], w[k + 1] + w[k + 5],
                                     fmaf(g[k],  w[k + 2] + w[k + 4],
                                                 w[k + 3])));
                    if      (j == 0) s0[k] = rs;
                    else if (j == 1) s1[k] = rs;
                    else if (j == 2) s2[k] = rs;
                    else if (j == 3) s3[k] = rs;
                    else if (j == 4) s2[k] = s2[k] + rs;
                    else if (j == 5) s1[k] = s1[k] + rs;
                    else             s0[k] = s0[k] + rs;
                }
            }

            // vertical combine — same association as rounds 0-8
            float res[4];
            #pragma unroll
            for (int k = 0; k < 4; ++k) {
                res[k] = fmaf(p9[k], s0[k],
                         fmaf(p4[k], s1[k],
                         fmaf(g[k],  s2[k], s3[k]))) * inv2[k];
            }
            *(float4*)(outp + (size_t)(rg + o) * NW + colbase) =
                make_float4(res[0], res[1], res[2], res[3]);

            // refill the dead slot: ONE b128 (own 4 columns only)
            if (o < 7) {
                const float4 a = *(const float4*)&ldsc[(wv * 8 + o + 7) * LROW + colbase];
                win[o % 7][0] = a.x; win[o % 7][1] = a.y;
                win[o % 7][2] = a.z; win[o % 7][3] = a.w;
            }
        }
    }
}

extern "C" void kernel_launch(void* const* d_in, const int* in_sizes, int n_in,
                              void* d_out, int out_size, void* d_ws, size_t ws_size,
                              hipStream_t stream) {
    const float* x     = (const float*)d_in[0];
    const float* persp = (const float*)d_in[1];
    const float* alpha = (const float*)d_in[2];
    const float* beta  = (const float*)d_in[3];
    const float* gamma = (const float*)d_in[4];
    float* outp        = (float*)d_out;
    float* wg          = (float*)d_ws;       // 4*256*256 floats = 1 MiB

    wprep<<<dim3((NB * NH * NW) / 1024), dim3(256), 0, stream>>>(persp, alpha, beta, gamma, wg);
    // 16 c-groups x 8 h-tiles x 4 batches = 512 blocks = 2/CU (LDS-fit: 155.6/160 KB)
    adaptive_gauss7<<<dim3(NC / CPB, NH / TH, NB), dim3(256), 0, stream>>>(x, wg, outp);
}